// Round 2
// baseline (1080.226 us; speedup 1.0000x reference)
//
#include <hip/hip_runtime.h>
#include <math.h>

#define NUM_E 8
#define NTOK  32768      // B*T = 8*4096
#define TSEQ  4096
#define DM    512
#define DF    2048
#define CAP   6144       // per-bucket capacity (avg 4096, binomial sigma ~60)

typedef unsigned short ushort_t;
typedef __attribute__((ext_vector_type(8))) short short8;
typedef __attribute__((ext_vector_type(4))) float floatx4;

__device__ __forceinline__ unsigned short f2bf(float f){
  union { float f; unsigned int u; } v; v.f = f;
  unsigned int u = v.u;
  unsigned int r = (u + 0x7FFFu + ((u >> 16) & 1u)) >> 16;  // RNE
  return (unsigned short)r;
}

__device__ __forceinline__ void gld_lds16(const void* g, void* l){
  __builtin_amdgcn_global_load_lds(
      (const __attribute__((address_space(1))) unsigned int*)g,
      (__attribute__((address_space(3))) unsigned int*)l, 16, 0, 0);
}

__global__ void k_init(int* cnt){
  if (threadIdx.x < NUM_E) cnt[threadIdx.x] = 0;
}

__global__ void k_route(const int* __restrict__ tok, float* __restrict__ ids_out,
                        int* __restrict__ cnt, int* __restrict__ list){
  int flat = blockIdx.x * blockDim.x + threadIdx.x;   // 0..NTOK-1
  int b = flat >> 12;                                  // T = 4096
  int t = tok[flat];
  int base = b * TSEQ + t;                             // b*T + token
  int e0 = base & 7;
  int e1 = (base + 1) & 7;
  ids_out[2*flat]   = (float)e0;
  ids_out[2*flat+1] = (float)e1;
  int pos = atomicAdd(&cnt[e0], 1);
  if (pos < CAP) list[e0*CAP + pos] = flat;
}

__global__ void k_finalize(const int* __restrict__ cnt, int* __restrict__ off,
                           float* __restrict__ counts_out){
  int tid = threadIdx.x;
  if (tid == 0){
    int s = 0;
    for (int c = 0; c < NUM_E; c++){ off[c] = s; s += cnt[c]; }
    off[NUM_E] = s;                                    // total sentinel
  }
  if (tid < NUM_E)
    counts_out[tid] = (float)(cnt[tid] + cnt[(tid + 7) & 7]); // slot0(bucket e) + slot1(bucket e-1)
}

__global__ void k_convert_x(const float* __restrict__ x, ushort_t* __restrict__ xb){
  int i = blockIdx.x * blockDim.x + threadIdx.x;       // one float4 per thread
  float4 v = ((const float4*)x)[i];
  ushort4 o;
  o.x = f2bf(v.x); o.y = f2bf(v.y); o.z = f2bf(v.z); o.w = f2bf(v.w);
  ((ushort4*)xb)[i] = o;
}

// in: [E][R][C] fp32  ->  out: [E][C][R] bf16
__global__ void k_transpose_cvt(const float* __restrict__ in, ushort_t* __restrict__ out,
                                int R, int C){
  __shared__ ushort_t s[64][65];
  int e = blockIdx.z;
  int c0 = blockIdx.x * 64, r0 = blockIdx.y * 64;
  const float* ine = in + (size_t)e * R * C;
  ushort_t* oute = out + (size_t)e * R * C;
  int tx = threadIdx.x & 63, ty = threadIdx.x >> 6;
  for (int rr = ty; rr < 64; rr += 4)
    s[rr][tx] = f2bf(ine[(size_t)(r0+rr)*C + c0 + tx]);
  __syncthreads();
  for (int cc = ty; cc < 64; cc += 4)
    oute[(size_t)(c0+cc)*R + r0 + tx] = s[tx][cc];
}

// GEMM1: for bucket c (phase-relative), slot s (expert e=(c+s)%8):
//   H[(off[c]-off[c0])+i][s*DF + n] = gelu( x[list[c][i]] @ W1[e] + b1[e] )   (bf16)
__global__ __launch_bounds__(256) void k_gemm1(
    const ushort_t* __restrict__ xb, const ushort_t* __restrict__ w1t,
    const float* __restrict__ b1,
    const int* __restrict__ cnt, const int* __restrict__ off,
    const int* __restrict__ list, ushort_t* __restrict__ H, int c0)
{
  int c = c0 + (blockIdx.z >> 1), slot = blockIdx.z & 1;
  int e = (c + slot) & 7;
  int n_c = cnt[c];
  int m0 = blockIdx.x * 128;
  if (m0 >= n_c) return;
  int n0 = blockIdx.y * 128;

  __shared__ alignas(16) ushort_t As[128*64];
  __shared__ alignas(16) ushort_t Bs[128*64];
  __shared__ unsigned int rowoff[128];

  int tid = threadIdx.x;
  int lane = tid & 63, w = tid >> 6;

  if (tid < 128){
    int i = m0 + tid;
    int tk = list[c*CAP + ((i < n_c) ? i : 0)];
    rowoff[tid] = (unsigned int)tk * (DM*2);
  }
  __syncthreads();

  unsigned int aoff[4], boff[4];
  const char* w1te = (const char*)w1t + (size_t)e * ((size_t)DF*DM*2);
  #pragma unroll
  for (int j = 0; j < 4; j++){
    int r = j*32 + w*8 + (lane >> 3);
    aoff[j] = rowoff[r] + (unsigned int)(lane & 7)*16u;
    boff[j] = (unsigned int)(n0 + r) * (DM*2) + (unsigned int)(lane & 7)*16u;
  }

  floatx4 acc[4][4];
  #pragma unroll
  for (int a = 0; a < 4; a++)
    #pragma unroll
    for (int q = 0; q < 4; q++) acc[a][q] = floatx4{0.f,0.f,0.f,0.f};

  int wr = w >> 1, wc = w & 1;
  int col = lane & 15, quad = lane >> 4;
  const ushort_t* Abase = As + (wr*64 + col)*64 + quad*8;
  const ushort_t* Bbase = Bs + (wc*64 + col)*64 + quad*8;
  char* AsW = (char*)As + w*1024;
  char* BsW = (char*)Bs + w*1024;

  for (int k0 = 0; k0 < DM; k0 += 64){
    #pragma unroll
    for (int j = 0; j < 4; j++){
      gld_lds16((const char*)xb + aoff[j] + k0*2, AsW + j*4096);
      gld_lds16(w1te + boff[j] + k0*2, BsW + j*4096);
    }
    __syncthreads();
    #pragma unroll
    for (int ks = 0; ks < 2; ks++){
      short8 a[4], bfr[4];
      #pragma unroll
      for (int mi = 0; mi < 4; mi++)
        a[mi] = *(const short8*)(Abase + mi*16*64 + ks*32);
      #pragma unroll
      for (int ni = 0; ni < 4; ni++)
        bfr[ni] = *(const short8*)(Bbase + ni*16*64 + ks*32);
      #pragma unroll
      for (int mi = 0; mi < 4; mi++)
        #pragma unroll
        for (int ni = 0; ni < 4; ni++)
          acc[mi][ni] = __builtin_amdgcn_mfma_f32_16x16x32_bf16(a[mi], bfr[ni], acc[mi][ni], 0, 0, 0);
    }
    __syncthreads();
  }

  int hbase = off[c] - off[c0];
  const float* b1e = b1 + e*DF;
  #pragma unroll
  for (int mi = 0; mi < 4; mi++){
    #pragma unroll
    for (int r = 0; r < 4; r++){
      int m = wr*64 + mi*16 + quad*4 + r;
      int i = m0 + m;
      if (i < n_c){
        size_t hrow = (size_t)(hbase + i)*(2*DF) + (size_t)slot*DF + n0 + wc*64;
        #pragma unroll
        for (int ni = 0; ni < 4; ni++){
          int nl = ni*16 + col;
          float v = acc[mi][ni][r] + b1e[n0 + wc*64 + nl];
          v = 0.5f * v * (1.0f + erff(v * 0.70710678118f));   // exact gelu
          H[hrow + nl] = f2bf(v);
        }
      }
    }
  }
}

// GEMM2: for bucket c (experts c, c+1):
//   out[list[c][i]][n] = 0.25*( H[(off[c]-off[c0])+i][0:4096] @ [W2[c];W2[c+1]] + b2[c] + b2[c+1] )
__global__ __launch_bounds__(256) void k_gemm2(
    const ushort_t* __restrict__ H, const ushort_t* __restrict__ w2t,
    const float* __restrict__ b2,
    const int* __restrict__ cnt, const int* __restrict__ off,
    const int* __restrict__ list, float* __restrict__ out, int c0, int nb)
{
  int c = c0 + blockIdx.z;
  int e1 = (c + 1) & 7;
  int n_c = cnt[c];
  int m0 = blockIdx.x * 128;
  if (m0 >= n_c) return;
  int n0 = blockIdx.y * 128;

  __shared__ alignas(16) ushort_t As[128*64];
  __shared__ alignas(16) ushort_t Bs[128*64];
  __shared__ int rowtok[128];

  int tid = threadIdx.x;
  int lane = tid & 63, w = tid >> 6;
  int rowbase = off[c] - off[c0];
  int phaseTok = off[c0 + nb] - off[c0];

  if (tid < 128){
    int i = m0 + tid;
    rowtok[tid] = list[c*CAP + ((i < n_c) ? i : 0)];
  }

  unsigned int aoff[4], boff[4];
  #pragma unroll
  for (int j = 0; j < 4; j++){
    int r = j*32 + w*8 + (lane >> 3);
    int rg = rowbase + m0 + r;
    if (rg > phaseTok - 1) rg = phaseTok - 1;           // stay inside phase H
    aoff[j] = (unsigned int)rg * (2*DF*2) + (unsigned int)(lane & 7)*16u;
    boff[j] = (unsigned int)(n0 + r) * (DF*2) + (unsigned int)(lane & 7)*16u;
  }
  const char* bb0 = (const char*)w2t + (size_t)c  * ((size_t)DM*DF*2);
  const char* bb1 = (const char*)w2t + (size_t)e1 * ((size_t)DM*DF*2);

  floatx4 acc[4][4];
  #pragma unroll
  for (int a = 0; a < 4; a++)
    #pragma unroll
    for (int q = 0; q < 4; q++) acc[a][q] = floatx4{0.f,0.f,0.f,0.f};

  int wr = w >> 1, wc = w & 1;
  int col = lane & 15, quad = lane >> 4;
  const ushort_t* Abase = As + (wr*64 + col)*64 + quad*8;
  const ushort_t* Bbase = Bs + (wc*64 + col)*64 + quad*8;
  char* AsW = (char*)As + w*1024;
  char* BsW = (char*)Bs + w*1024;

  for (int k0 = 0; k0 < 2*DF; k0 += 64){
    const char* bb = (k0 < DF) ? (bb0 + k0*2) : (bb1 + (k0 - DF)*2);
    #pragma unroll
    for (int j = 0; j < 4; j++){
      gld_lds16((const char*)H + aoff[j] + k0*2, AsW + j*4096);
      gld_lds16(bb + boff[j], BsW + j*4096);
    }
    __syncthreads();
    #pragma unroll
    for (int ks = 0; ks < 2; ks++){
      short8 a[4], bfr[4];
      #pragma unroll
      for (int mi = 0; mi < 4; mi++)
        a[mi] = *(const short8*)(Abase + mi*16*64 + ks*32);
      #pragma unroll
      for (int ni = 0; ni < 4; ni++)
        bfr[ni] = *(const short8*)(Bbase + ni*16*64 + ks*32);
      #pragma unroll
      for (int mi = 0; mi < 4; mi++)
        #pragma unroll
        for (int ni = 0; ni < 4; ni++)
          acc[mi][ni] = __builtin_amdgcn_mfma_f32_16x16x32_bf16(a[mi], bfr[ni], acc[mi][ni], 0, 0, 0);
    }
    __syncthreads();
  }

  const float* b2a = b2 + c*DM;
  const float* b2b = b2 + e1*DM;
  #pragma unroll
  for (int mi = 0; mi < 4; mi++){
    #pragma unroll
    for (int r = 0; r < 4; r++){
      int m = wr*64 + mi*16 + quad*4 + r;
      int i = m0 + m;
      if (i < n_c){
        int tk = rowtok[m];
        float* orow = out + (size_t)tk*DM + n0 + wc*64;
        #pragma unroll
        for (int ni = 0; ni < 4; ni++){
          int nl = ni*16 + col;
          int gn = n0 + wc*64 + nl;
          orow[nl] = 0.25f * (acc[mi][ni][r] + b2a[gn] + b2b[gn]);
        }
      }
    }
  }
}

extern "C" void kernel_launch(void* const* d_in, const int* in_sizes, int n_in,
                              void* d_out, int out_size, void* d_ws, size_t ws_size,
                              hipStream_t stream){
  const float* x   = (const float*)d_in[0];
  const int*   tok = (const int*)d_in[1];
  const float* W1  = (const float*)d_in[2];
  const float* b1  = (const float*)d_in[3];
  const float* W2  = (const float*)d_in[4];
  const float* b2  = (const float*)d_in[5];

  float* out        = (float*)d_out;                       // (B,T,D) f32
  float* ids_out    = out + (size_t)NTOK*DM;               // (B,T,2) as f32
  float* counts_out = ids_out + (size_t)NTOK*2;            // (E,)    as f32

  char* ws = (char*)d_ws;
  int* cnt  = (int*)ws;                                    // 8
  int* off  = cnt + 16;                                    // 9 (incl. total)
  int* list = (int*)(ws + 4096);                           // 8*CAP ints (192 KB)
  ushort_t* w1t = (ushort_t*)(ws + (1 << 20));             // [E][DF][DM] bf16 (16 MB)
  ushort_t* w2t = w1t + (size_t)NUM_E*DF*DM;               // [E][DM][DF] bf16 (16 MB)
  ushort_t* xb  = w2t + (size_t)NUM_E*DM*DF;               // [NTOK][DM]  bf16 (32 MB)
  ushort_t* H   = (ushort_t*)(ws + (65ull << 20));         // phase H (bf16)

  // choose phase width nb so the H region fits in ws
  size_t fixed_b = 65ull << 20;
  size_t avail = (ws_size > fixed_b) ? (ws_size - fixed_b) : 0;
  int nb = 0;
  for (int cand = 8; cand >= 1; cand >>= 1){
    size_t need = ((size_t)cand * 4096 + 1024) * (size_t)(2*DF) * 2;
    if (need <= avail){ nb = cand; break; }
  }
  if (nb == 0) nb = 1;   // last resort

  k_init<<<1, 64, 0, stream>>>(cnt);
  k_route<<<NTOK/256, 256, 0, stream>>>(tok, ids_out, cnt, list);
  k_finalize<<<1, 64, 0, stream>>>(cnt, off, counts_out);
  k_convert_x<<<(NTOK*DM/4)/256, 256, 0, stream>>>(x, xb);
  k_transpose_cvt<<<dim3(DF/64, DM/64, NUM_E), 256, 0, stream>>>(W1, w1t, DM, DF);
  k_transpose_cvt<<<dim3(DM/64, DF/64, NUM_E), 256, 0, stream>>>(W2, w2t, DF, DM);

  for (int c0 = 0; c0 < NUM_E; c0 += nb){
    k_gemm1<<<dim3(CAP/128, DF/128, 2*nb), 256, 0, stream>>>(
        xb, w1t, b1, cnt, off, list, H, c0);
    k_gemm2<<<dim3(CAP/128, DM/128, nb), 256, 0, stream>>>(
        H, w2t, b2, cnt, off, list, out, c0, nb);
  }
}

// Round 3
// 754.505 us; speedup vs baseline: 1.4317x; 1.4317x over previous
//
#include <hip/hip_runtime.h>
#include <math.h>

#define NUM_E 8
#define NTOK  32768      // B*T = 8*4096
#define TSEQ  4096
#define DM    512
#define DF    2048
#define CAP   6144       // per-bucket capacity (avg 4096, binomial sigma ~60)

typedef unsigned short ushort_t;
typedef __attribute__((ext_vector_type(8))) short short8;
typedef __attribute__((ext_vector_type(4))) float floatx4;

__device__ __forceinline__ unsigned short f2bf(float f){
  union { float f; unsigned int u; } v; v.f = f;
  unsigned int u = v.u;
  unsigned int r = (u + 0x7FFFu + ((u >> 16) & 1u)) >> 16;  // RNE
  return (unsigned short)r;
}

__device__ __forceinline__ void gld_lds16(const void* g, void* l){
  __builtin_amdgcn_global_load_lds(
      (const __attribute__((address_space(1))) unsigned int*)g,
      (__attribute__((address_space(3))) unsigned int*)l, 16, 0, 0);
}

__global__ void k_init(int* cnt){
  if (threadIdx.x < NUM_E) cnt[threadIdx.x] = 0;
}

__global__ void k_route(const int* __restrict__ tok, float* __restrict__ ids_out,
                        int* __restrict__ cnt, int* __restrict__ list){
  int flat = blockIdx.x * blockDim.x + threadIdx.x;   // 0..NTOK-1
  int b = flat >> 12;                                  // T = 4096
  int t = tok[flat];
  int base = b * TSEQ + t;                             // b*T + token
  int e0 = base & 7;
  int e1 = (base + 1) & 7;
  ids_out[2*flat]   = (float)e0;
  ids_out[2*flat+1] = (float)e1;
  int pos = atomicAdd(&cnt[e0], 1);
  if (pos < CAP) list[e0*CAP + pos] = flat;
}

__global__ void k_finalize(const int* __restrict__ cnt, int* __restrict__ off,
                           float* __restrict__ counts_out){
  int tid = threadIdx.x;
  if (tid == 0){
    int s = 0;
    for (int c = 0; c < NUM_E; c++){ off[c] = s; s += cnt[c]; }
    off[NUM_E] = s;                                    // total sentinel
  }
  if (tid < NUM_E)
    counts_out[tid] = (float)(cnt[tid] + cnt[(tid + 7) & 7]); // slot0(bucket e) + slot1(bucket e-1)
}

__global__ void k_convert_x(const float* __restrict__ x, ushort_t* __restrict__ xb){
  int i = blockIdx.x * blockDim.x + threadIdx.x;       // one float4 per thread
  float4 v = ((const float4*)x)[i];
  ushort4 o;
  o.x = f2bf(v.x); o.y = f2bf(v.y); o.z = f2bf(v.z); o.w = f2bf(v.w);
  ((ushort4*)xb)[i] = o;
}

// in: [E][R][C] fp32  ->  out: [E][C][R] bf16
__global__ void k_transpose_cvt(const float* __restrict__ in, ushort_t* __restrict__ out,
                                int R, int C){
  __shared__ ushort_t s[64][65];
  int e = blockIdx.z;
  int c0 = blockIdx.x * 64, r0 = blockIdx.y * 64;
  const float* ine = in + (size_t)e * R * C;
  ushort_t* oute = out + (size_t)e * R * C;
  int tx = threadIdx.x & 63, ty = threadIdx.x >> 6;
  for (int rr = ty; rr < 64; rr += 4)
    s[rr][tx] = f2bf(ine[(size_t)(r0+rr)*C + c0 + tx]);
  __syncthreads();
  for (int cc = ty; cc < 64; cc += 4)
    oute[(size_t)(c0+cc)*R + r0 + tx] = s[tx][cc];
}

// LDS tile layout (both GEMMs): 128 rows x 64 ushort, row-major, but within each
// row the eight 16B chunks are XOR-swizzled: chunk c of row r sits at slot c^(r&7).
// Staging lane L (in an 8-row/1024B block) therefore fetches global chunk
// (L&7)^(L>>3); fragment reads use ((quad+4*ks)^(col&7)) — spreads 64 lanes
// evenly 8-per-bank-group (minimum aliasing for 1024B/instr).

// GEMM1: for bucket c (phase-relative), slot s (expert e=(c+s)%8):
//   H[(off[c]-off[c0])+i][s*DF + n] = gelu( x[list[c][i]] @ W1[e] + b1[e] )   (bf16)
__global__ __launch_bounds__(256, 4) void k_gemm1(
    const ushort_t* __restrict__ xb, const ushort_t* __restrict__ w1t,
    const float* __restrict__ b1,
    const int* __restrict__ cnt, const int* __restrict__ off,
    const int* __restrict__ list, ushort_t* __restrict__ H, int c0)
{
  int c = c0 + (blockIdx.z >> 1), slot = blockIdx.z & 1;
  int e = (c + slot) & 7;
  int n_c = cnt[c];
  int m0 = blockIdx.x * 128;
  if (m0 >= n_c) return;
  int n0 = blockIdx.y * 128;

  __shared__ alignas(16) ushort_t As[128*64];
  __shared__ alignas(16) ushort_t Bs[128*64];
  __shared__ unsigned int rowoff[128];

  int tid = threadIdx.x;
  int lane = tid & 63, w = tid >> 6;

  if (tid < 128){
    int i = m0 + tid;
    int tk = list[c*CAP + ((i < n_c) ? i : 0)];
    rowoff[tid] = (unsigned int)tk * (DM*2);
  }
  __syncthreads();

  int rl = lane >> 3;                 // row within 8-row staging block
  int cc = (lane & 7) ^ rl;           // swizzled source chunk
  unsigned int aoff[4], boff[4];
  const char* w1te = (const char*)w1t + (size_t)e * ((size_t)DF*DM*2);
  #pragma unroll
  for (int j = 0; j < 4; j++){
    int r = j*32 + w*8 + rl;
    aoff[j] = rowoff[r] + (unsigned int)cc*16u;
    boff[j] = (unsigned int)(n0 + r) * (DM*2) + (unsigned int)cc*16u;
  }

  floatx4 acc[4][4];
  #pragma unroll
  for (int a = 0; a < 4; a++)
    #pragma unroll
    for (int q = 0; q < 4; q++) acc[a][q] = floatx4{0.f,0.f,0.f,0.f};

  int wr = w >> 1, wc = w & 1;
  int col = lane & 15, quad = lane >> 4;
  int xa = col & 7;
  const ushort_t* A0 = As + (wr*64 + col)*64 + (quad ^ xa)*8;        // ks=0
  const ushort_t* A1 = As + (wr*64 + col)*64 + ((quad + 4) ^ xa)*8;  // ks=1
  const ushort_t* B0 = Bs + (wc*64 + col)*64 + (quad ^ xa)*8;
  const ushort_t* B1 = Bs + (wc*64 + col)*64 + ((quad + 4) ^ xa)*8;
  char* AsW = (char*)As + w*1024;
  char* BsW = (char*)Bs + w*1024;

  for (int k0 = 0; k0 < DM; k0 += 64){
    #pragma unroll
    for (int j = 0; j < 4; j++){
      gld_lds16((const char*)xb + aoff[j] + k0*2, AsW + j*4096);
      gld_lds16(w1te + boff[j] + k0*2, BsW + j*4096);
    }
    __syncthreads();
    {
      short8 a[4], bfr[4];
      #pragma unroll
      for (int mi = 0; mi < 4; mi++) a[mi] = *(const short8*)(A0 + mi*1024);
      #pragma unroll
      for (int ni = 0; ni < 4; ni++) bfr[ni] = *(const short8*)(B0 + ni*1024);
      #pragma unroll
      for (int mi = 0; mi < 4; mi++)
        #pragma unroll
        for (int ni = 0; ni < 4; ni++)
          acc[mi][ni] = __builtin_amdgcn_mfma_f32_16x16x32_bf16(a[mi], bfr[ni], acc[mi][ni], 0, 0, 0);
      #pragma unroll
      for (int mi = 0; mi < 4; mi++) a[mi] = *(const short8*)(A1 + mi*1024);
      #pragma unroll
      for (int ni = 0; ni < 4; ni++) bfr[ni] = *(const short8*)(B1 + ni*1024);
      #pragma unroll
      for (int mi = 0; mi < 4; mi++)
        #pragma unroll
        for (int ni = 0; ni < 4; ni++)
          acc[mi][ni] = __builtin_amdgcn_mfma_f32_16x16x32_bf16(a[mi], bfr[ni], acc[mi][ni], 0, 0, 0);
    }
    __syncthreads();
  }

  int hbase = off[c] - off[c0];
  const float* b1e = b1 + e*DF;
  #pragma unroll
  for (int mi = 0; mi < 4; mi++){
    #pragma unroll
    for (int r = 0; r < 4; r++){
      int m = wr*64 + mi*16 + quad*4 + r;
      int i = m0 + m;
      if (i < n_c){
        size_t hrow = (size_t)(hbase + i)*(2*DF) + (size_t)slot*DF + n0 + wc*64;
        #pragma unroll
        for (int ni = 0; ni < 4; ni++){
          int nl = ni*16 + col;
          float v = acc[mi][ni][r] + b1e[n0 + wc*64 + nl];
          v = 0.5f * v * (1.0f + erff(v * 0.70710678118f));   // exact gelu
          H[hrow + nl] = f2bf(v);
        }
      }
    }
  }
}

// GEMM2: for bucket c (experts c, c+1):
//   out[list[c][i]][n] = 0.25*( H[(off[c]-off[c0])+i][0:4096] @ [W2[c];W2[c+1]] + b2[c] + b2[c+1] )
__global__ __launch_bounds__(256, 4) void k_gemm2(
    const ushort_t* __restrict__ H, const ushort_t* __restrict__ w2t,
    const float* __restrict__ b2,
    const int* __restrict__ cnt, const int* __restrict__ off,
    const int* __restrict__ list, float* __restrict__ out, int c0, int nb)
{
  int c = c0 + blockIdx.z;
  int e1 = (c + 1) & 7;
  int n_c = cnt[c];
  int m0 = blockIdx.x * 128;
  if (m0 >= n_c) return;
  int n0 = blockIdx.y * 128;

  __shared__ alignas(16) ushort_t As[128*64];
  __shared__ alignas(16) ushort_t Bs[128*64];
  __shared__ int rowtok[128];

  int tid = threadIdx.x;
  int lane = tid & 63, w = tid >> 6;
  int rowbase = off[c] - off[c0];
  int phaseTok = off[c0 + nb] - off[c0];

  if (tid < 128){
    int i = m0 + tid;
    rowtok[tid] = list[c*CAP + ((i < n_c) ? i : 0)];
  }

  int rl = lane >> 3;
  int cc = (lane & 7) ^ rl;
  unsigned int aoff[4], boff[4];
  #pragma unroll
  for (int j = 0; j < 4; j++){
    int r = j*32 + w*8 + rl;
    int rg = rowbase + m0 + r;
    if (rg > phaseTok - 1) rg = phaseTok - 1;           // stay inside phase H
    aoff[j] = (unsigned int)rg * (2*DF*2) + (unsigned int)cc*16u;
    boff[j] = (unsigned int)(n0 + r) * (DF*2) + (unsigned int)cc*16u;
  }
  const char* bb0 = (const char*)w2t + (size_t)c  * ((size_t)DM*DF*2);
  const char* bb1 = (const char*)w2t + (size_t)e1 * ((size_t)DM*DF*2);

  floatx4 acc[4][4];
  #pragma unroll
  for (int a = 0; a < 4; a++)
    #pragma unroll
    for (int q = 0; q < 4; q++) acc[a][q] = floatx4{0.f,0.f,0.f,0.f};

  int wr = w >> 1, wc = w & 1;
  int col = lane & 15, quad = lane >> 4;
  int xa = col & 7;
  const ushort_t* A0 = As + (wr*64 + col)*64 + (quad ^ xa)*8;
  const ushort_t* A1 = As + (wr*64 + col)*64 + ((quad + 4) ^ xa)*8;
  const ushort_t* B0 = Bs + (wc*64 + col)*64 + (quad ^ xa)*8;
  const ushort_t* B1 = Bs + (wc*64 + col)*64 + ((quad + 4) ^ xa)*8;
  char* AsW = (char*)As + w*1024;
  char* BsW = (char*)Bs + w*1024;

  for (int k0 = 0; k0 < 2*DF; k0 += 64){
    const char* bb = (k0 < DF) ? (bb0 + k0*2) : (bb1 + (k0 - DF)*2);
    #pragma unroll
    for (int j = 0; j < 4; j++){
      gld_lds16((const char*)H + aoff[j] + k0*2, AsW + j*4096);
      gld_lds16(bb + boff[j], BsW + j*4096);
    }
    __syncthreads();
    {
      short8 a[4], bfr[4];
      #pragma unroll
      for (int mi = 0; mi < 4; mi++) a[mi] = *(const short8*)(A0 + mi*1024);
      #pragma unroll
      for (int ni = 0; ni < 4; ni++) bfr[ni] = *(const short8*)(B0 + ni*1024);
      #pragma unroll
      for (int mi = 0; mi < 4; mi++)
        #pragma unroll
        for (int ni = 0; ni < 4; ni++)
          acc[mi][ni] = __builtin_amdgcn_mfma_f32_16x16x32_bf16(a[mi], bfr[ni], acc[mi][ni], 0, 0, 0);
      #pragma unroll
      for (int mi = 0; mi < 4; mi++) a[mi] = *(const short8*)(A1 + mi*1024);
      #pragma unroll
      for (int ni = 0; ni < 4; ni++) bfr[ni] = *(const short8*)(B1 + ni*1024);
      #pragma unroll
      for (int mi = 0; mi < 4; mi++)
        #pragma unroll
        for (int ni = 0; ni < 4; ni++)
          acc[mi][ni] = __builtin_amdgcn_mfma_f32_16x16x32_bf16(a[mi], bfr[ni], acc[mi][ni], 0, 0, 0);
    }
    __syncthreads();
  }

  const float* b2a = b2 + c*DM;
  const float* b2b = b2 + e1*DM;
  #pragma unroll
  for (int mi = 0; mi < 4; mi++){
    #pragma unroll
    for (int r = 0; r < 4; r++){
      int m = wr*64 + mi*16 + quad*4 + r;
      int i = m0 + m;
      if (i < n_c){
        int tk = rowtok[m];
        float* orow = out + (size_t)tk*DM + n0 + wc*64;
        #pragma unroll
        for (int ni = 0; ni < 4; ni++){
          int nl = ni*16 + col;
          int gn = n0 + wc*64 + nl;
          orow[nl] = 0.25f * (acc[mi][ni][r] + b2a[gn] + b2b[gn]);
        }
      }
    }
  }
}

extern "C" void kernel_launch(void* const* d_in, const int* in_sizes, int n_in,
                              void* d_out, int out_size, void* d_ws, size_t ws_size,
                              hipStream_t stream){
  const float* x   = (const float*)d_in[0];
  const int*   tok = (const int*)d_in[1];
  const float* W1  = (const float*)d_in[2];
  const float* b1  = (const float*)d_in[3];
  const float* W2  = (const float*)d_in[4];
  const float* b2  = (const float*)d_in[5];

  float* out        = (float*)d_out;                       // (B,T,D) f32
  float* ids_out    = out + (size_t)NTOK*DM;               // (B,T,2) as f32
  float* counts_out = ids_out + (size_t)NTOK*2;            // (E,)    as f32

  char* ws = (char*)d_ws;
  int* cnt  = (int*)ws;                                    // 8
  int* off  = cnt + 16;                                    // 9 (incl. total)
  int* list = (int*)(ws + 4096);                           // 8*CAP ints (192 KB)
  ushort_t* w1t = (ushort_t*)(ws + (1 << 20));             // [E][DF][DM] bf16 (16 MB)
  ushort_t* w2t = w1t + (size_t)NUM_E*DF*DM;               // [E][DM][DF] bf16 (16 MB)
  ushort_t* xb  = w2t + (size_t)NUM_E*DM*DF;               // [NTOK][DM]  bf16 (32 MB)
  ushort_t* H   = (ushort_t*)(ws + (65ull << 20));         // phase H (bf16)

  // choose phase width nb so the H region fits in ws
  size_t fixed_b = 65ull << 20;
  size_t avail = (ws_size > fixed_b) ? (ws_size - fixed_b) : 0;
  int nb = 0;
  for (int cand = 8; cand >= 1; cand >>= 1){
    size_t need = ((size_t)cand * 4096 + 1024) * (size_t)(2*DF) * 2;
    if (need <= avail){ nb = cand; break; }
  }
  if (nb == 0) nb = 1;   // last resort

  k_init<<<1, 64, 0, stream>>>(cnt);
  k_route<<<NTOK/256, 256, 0, stream>>>(tok, ids_out, cnt, list);
  k_finalize<<<1, 64, 0, stream>>>(cnt, off, counts_out);
  k_convert_x<<<(NTOK*DM/4)/256, 256, 0, stream>>>(x, xb);
  k_transpose_cvt<<<dim3(DF/64, DM/64, NUM_E), 256, 0, stream>>>(W1, w1t, DM, DF);
  k_transpose_cvt<<<dim3(DM/64, DF/64, NUM_E), 256, 0, stream>>>(W2, w2t, DF, DM);

  for (int c0 = 0; c0 < NUM_E; c0 += nb){
    k_gemm1<<<dim3(CAP/128, DF/128, 2*nb), 256, 0, stream>>>(
        xb, w1t, b1, cnt, off, list, H, c0);
    k_gemm2<<<dim3(CAP/128, DM/128, nb), 256, 0, stream>>>(
        H, w2t, b2, cnt, off, list, out, c0, nb);
  }
}

// Round 4
// 697.928 us; speedup vs baseline: 1.5478x; 1.0811x over previous
//
#include <hip/hip_runtime.h>
#include <math.h>

#define NUM_E 8
#define NTOK  32768      // B*T = 8*4096
#define TSEQ  4096
#define DM    512
#define DF    2048
#define CAP   6144       // per-bucket capacity (avg 4096, binomial sigma ~60)

typedef unsigned short ushort_t;
typedef __attribute__((ext_vector_type(8))) short short8;
typedef __attribute__((ext_vector_type(4))) float floatx4;

__device__ __forceinline__ unsigned short f2bf(float f){
  union { float f; unsigned int u; } v; v.f = f;
  unsigned int u = v.u;
  unsigned int r = (u + 0x7FFFu + ((u >> 16) & 1u)) >> 16;  // RNE
  return (unsigned short)r;
}

// tanh-approx gelu, reduced: 0.5h(1+tanh(0.79788456(h+0.044715h^3)))
//                          = h * sigmoid(1.5957691h + 0.0713548163h^3)
// max |delta| vs exact erf-gelu ~2e-3 per element; propagated to out ~1e-3.
__device__ __forceinline__ float gelu_fast(float h){
  float z = h * (1.5957691216057308f + 0.0713548162726009f * h * h);
  float e = __expf(-z);
  return h * __builtin_amdgcn_rcpf(1.0f + e);
}

__device__ __forceinline__ void gld_lds16(const void* g, void* l){
  __builtin_amdgcn_global_load_lds(
      (const __attribute__((address_space(1))) unsigned int*)g,
      (__attribute__((address_space(3))) unsigned int*)l, 16, 0, 0);
}

__global__ void k_init(int* cnt){
  if (threadIdx.x < NUM_E) cnt[threadIdx.x] = 0;
}

__global__ void k_route(const int* __restrict__ tok, float* __restrict__ ids_out,
                        int* __restrict__ cnt, int* __restrict__ list){
  int flat = blockIdx.x * blockDim.x + threadIdx.x;   // 0..NTOK-1
  int b = flat >> 12;                                  // T = 4096
  int t = tok[flat];
  int base = b * TSEQ + t;                             // b*T + token
  int e0 = base & 7;
  int e1 = (base + 1) & 7;
  ids_out[2*flat]   = (float)e0;
  ids_out[2*flat+1] = (float)e1;
  int pos = atomicAdd(&cnt[e0], 1);
  if (pos < CAP) list[e0*CAP + pos] = flat;
}

__global__ void k_finalize(const int* __restrict__ cnt, int* __restrict__ off,
                           float* __restrict__ counts_out){
  int tid = threadIdx.x;
  if (tid == 0){
    int s = 0;
    for (int c = 0; c < NUM_E; c++){ off[c] = s; s += cnt[c]; }
    off[NUM_E] = s;                                    // total sentinel
  }
  if (tid < NUM_E)
    counts_out[tid] = (float)(cnt[tid] + cnt[(tid + 7) & 7]); // slot0(bucket e) + slot1(bucket e-1)
}

__global__ void k_convert_x(const float* __restrict__ x, ushort_t* __restrict__ xb){
  int i = blockIdx.x * blockDim.x + threadIdx.x;       // one float4 per thread
  float4 v = ((const float4*)x)[i];
  ushort4 o;
  o.x = f2bf(v.x); o.y = f2bf(v.y); o.z = f2bf(v.z); o.w = f2bf(v.w);
  ((ushort4*)xb)[i] = o;
}

// in: [E][R][C] fp32  ->  out: [E][C][R] bf16
__global__ void k_transpose_cvt(const float* __restrict__ in, ushort_t* __restrict__ out,
                                int R, int C){
  __shared__ ushort_t s[64][65];
  int e = blockIdx.z;
  int c0 = blockIdx.x * 64, r0 = blockIdx.y * 64;
  const float* ine = in + (size_t)e * R * C;
  ushort_t* oute = out + (size_t)e * R * C;
  int tx = threadIdx.x & 63, ty = threadIdx.x >> 6;
  for (int rr = ty; rr < 64; rr += 4)
    s[rr][tx] = f2bf(ine[(size_t)(r0+rr)*C + c0 + tx]);
  __syncthreads();
  for (int cc = ty; cc < 64; cc += 4)
    oute[(size_t)(c0+cc)*R + r0 + tx] = s[tx][cc];
}

// LDS tile layout (both GEMMs): 128 rows x 64 ushort, row-major; within each
// row the eight 16B chunks are XOR-swizzled: chunk c of row r sits at slot c^(r&7).
// Staging lane L fetches global chunk (L&7)^(L>>3); fragment reads use
// ((quad+4*ks)^(col&7)) — spreads 64 lanes 8-per-bank-group (conflict-free).

// GEMM1: for bucket c (phase-relative), slot s (expert e=(c+s)%8):
//   H[(off[c]-off[c0])+i][s*DF + n] = gelu( x[list[c][i]] @ W1[e] + b1[e] )   (bf16)
__global__ __launch_bounds__(256, 4) void k_gemm1(
    const ushort_t* __restrict__ xb, const ushort_t* __restrict__ w1t,
    const float* __restrict__ b1,
    const int* __restrict__ cnt, const int* __restrict__ off,
    const int* __restrict__ list, ushort_t* __restrict__ H, int c0)
{
  int c = c0 + (blockIdx.z >> 1), slot = blockIdx.z & 1;
  int e = (c + slot) & 7;
  int n_c = cnt[c];
  int m0 = blockIdx.x * 128;
  if (m0 >= n_c) return;
  int n0 = blockIdx.y * 128;

  __shared__ alignas(16) ushort_t As[128*64];
  __shared__ alignas(16) ushort_t Bs[128*64];
  __shared__ unsigned int rowoff[128];

  int tid = threadIdx.x;
  int lane = tid & 63, w = tid >> 6;

  if (tid < 128){
    int i = m0 + tid;
    int tk = list[c*CAP + ((i < n_c) ? i : 0)];
    rowoff[tid] = (unsigned int)tk * (DM*2);
  }
  __syncthreads();

  int rl = lane >> 3;                 // row within 8-row staging block
  int cc = (lane & 7) ^ rl;           // swizzled source chunk
  unsigned int aoff[4], boff[4];
  const char* w1te = (const char*)w1t + (size_t)e * ((size_t)DF*DM*2);
  #pragma unroll
  for (int j = 0; j < 4; j++){
    int r = j*32 + w*8 + rl;
    aoff[j] = rowoff[r] + (unsigned int)cc*16u;
    boff[j] = (unsigned int)(n0 + r) * (DM*2) + (unsigned int)cc*16u;
  }

  floatx4 acc[4][4];
  #pragma unroll
  for (int a = 0; a < 4; a++)
    #pragma unroll
    for (int q = 0; q < 4; q++) acc[a][q] = floatx4{0.f,0.f,0.f,0.f};

  int wr = w >> 1, wc = w & 1;
  int col = lane & 15, quad = lane >> 4;
  int xa = col & 7;
  const ushort_t* A0 = As + (wr*64 + col)*64 + (quad ^ xa)*8;        // ks=0
  const ushort_t* A1 = As + (wr*64 + col)*64 + ((quad + 4) ^ xa)*8;  // ks=1
  const ushort_t* B0 = Bs + (wc*64 + col)*64 + (quad ^ xa)*8;
  const ushort_t* B1 = Bs + (wc*64 + col)*64 + ((quad + 4) ^ xa)*8;
  char* AsW = (char*)As + w*1024;
  char* BsW = (char*)Bs + w*1024;

  for (int k0 = 0; k0 < DM; k0 += 64){
    #pragma unroll
    for (int j = 0; j < 4; j++){
      gld_lds16((const char*)xb + aoff[j] + k0*2, AsW + j*4096);
      gld_lds16(w1te + boff[j] + k0*2, BsW + j*4096);
    }
    __syncthreads();
    {
      short8 a[4], bfr[4];
      #pragma unroll
      for (int mi = 0; mi < 4; mi++) a[mi] = *(const short8*)(A0 + mi*1024);
      #pragma unroll
      for (int ni = 0; ni < 4; ni++) bfr[ni] = *(const short8*)(B0 + ni*1024);
      #pragma unroll
      for (int mi = 0; mi < 4; mi++)
        #pragma unroll
        for (int ni = 0; ni < 4; ni++)
          acc[mi][ni] = __builtin_amdgcn_mfma_f32_16x16x32_bf16(a[mi], bfr[ni], acc[mi][ni], 0, 0, 0);
      #pragma unroll
      for (int mi = 0; mi < 4; mi++) a[mi] = *(const short8*)(A1 + mi*1024);
      #pragma unroll
      for (int ni = 0; ni < 4; ni++) bfr[ni] = *(const short8*)(B1 + ni*1024);
      #pragma unroll
      for (int mi = 0; mi < 4; mi++)
        #pragma unroll
        for (int ni = 0; ni < 4; ni++)
          acc[mi][ni] = __builtin_amdgcn_mfma_f32_16x16x32_bf16(a[mi], bfr[ni], acc[mi][ni], 0, 0, 0);
    }
    __syncthreads();
  }

  int hbase = off[c] - off[c0];
  const float* b1e = b1 + e*DF;
  #pragma unroll
  for (int mi = 0; mi < 4; mi++){
    #pragma unroll
    for (int r = 0; r < 4; r++){
      int m = wr*64 + mi*16 + quad*4 + r;
      int i = m0 + m;
      if (i < n_c){
        size_t hrow = (size_t)(hbase + i)*(2*DF) + (size_t)slot*DF + n0 + wc*64;
        #pragma unroll
        for (int ni = 0; ni < 4; ni++){
          int nl = ni*16 + col;
          float v = acc[mi][ni][r] + b1e[n0 + wc*64 + nl];
          H[hrow + nl] = f2bf(gelu_fast(v));
        }
      }
    }
  }
}

// GEMM2: for bucket c (experts c, c+1):
//   out[list[c][i]][n] = 0.25*( H[(off[c]-off[c0])+i][0:4096] @ [W2[c];W2[c+1]] + b2[c] + b2[c+1] )
__global__ __launch_bounds__(256, 4) void k_gemm2(
    const ushort_t* __restrict__ H, const ushort_t* __restrict__ w2t,
    const float* __restrict__ b2,
    const int* __restrict__ cnt, const int* __restrict__ off,
    const int* __restrict__ list, float* __restrict__ out, int c0, int nb)
{
  int c = c0 + blockIdx.z;
  int e1 = (c + 1) & 7;
  int n_c = cnt[c];
  int m0 = blockIdx.x * 128;
  if (m0 >= n_c) return;
  int n0 = blockIdx.y * 128;

  __shared__ alignas(16) ushort_t As[128*64];
  __shared__ alignas(16) ushort_t Bs[128*64];
  __shared__ int rowtok[128];

  int tid = threadIdx.x;
  int lane = tid & 63, w = tid >> 6;
  int rowbase = off[c] - off[c0];
  int phaseTok = off[c0 + nb] - off[c0];

  if (tid < 128){
    int i = m0 + tid;
    rowtok[tid] = list[c*CAP + ((i < n_c) ? i : 0)];
  }

  int rl = lane >> 3;
  int cc = (lane & 7) ^ rl;
  unsigned int aoff[4], boff[4];
  #pragma unroll
  for (int j = 0; j < 4; j++){
    int r = j*32 + w*8 + rl;
    int rg = rowbase + m0 + r;
    if (rg > phaseTok - 1) rg = phaseTok - 1;           // stay inside phase H
    aoff[j] = (unsigned int)rg * (2*DF*2) + (unsigned int)cc*16u;
    boff[j] = (unsigned int)(n0 + r) * (DF*2) + (unsigned int)cc*16u;
  }
  const char* bb0 = (const char*)w2t + (size_t)c  * ((size_t)DM*DF*2);
  const char* bb1 = (const char*)w2t + (size_t)e1 * ((size_t)DM*DF*2);

  floatx4 acc[4][4];
  #pragma unroll
  for (int a = 0; a < 4; a++)
    #pragma unroll
    for (int q = 0; q < 4; q++) acc[a][q] = floatx4{0.f,0.f,0.f,0.f};

  int wr = w >> 1, wc = w & 1;
  int col = lane & 15, quad = lane >> 4;
  int xa = col & 7;
  const ushort_t* A0 = As + (wr*64 + col)*64 + (quad ^ xa)*8;
  const ushort_t* A1 = As + (wr*64 + col)*64 + ((quad + 4) ^ xa)*8;
  const ushort_t* B0 = Bs + (wc*64 + col)*64 + (quad ^ xa)*8;
  const ushort_t* B1 = Bs + (wc*64 + col)*64 + ((quad + 4) ^ xa)*8;
  char* AsW = (char*)As + w*1024;
  char* BsW = (char*)Bs + w*1024;

  for (int k0 = 0; k0 < 2*DF; k0 += 64){
    const char* bb = (k0 < DF) ? (bb0 + k0*2) : (bb1 + (k0 - DF)*2);
    #pragma unroll
    for (int j = 0; j < 4; j++){
      gld_lds16((const char*)H + aoff[j] + k0*2, AsW + j*4096);
      gld_lds16(bb + boff[j], BsW + j*4096);
    }
    __syncthreads();
    {
      short8 a[4], bfr[4];
      #pragma unroll
      for (int mi = 0; mi < 4; mi++) a[mi] = *(const short8*)(A0 + mi*1024);
      #pragma unroll
      for (int ni = 0; ni < 4; ni++) bfr[ni] = *(const short8*)(B0 + ni*1024);
      #pragma unroll
      for (int mi = 0; mi < 4; mi++)
        #pragma unroll
        for (int ni = 0; ni < 4; ni++)
          acc[mi][ni] = __builtin_amdgcn_mfma_f32_16x16x32_bf16(a[mi], bfr[ni], acc[mi][ni], 0, 0, 0);
      #pragma unroll
      for (int mi = 0; mi < 4; mi++) a[mi] = *(const short8*)(A1 + mi*1024);
      #pragma unroll
      for (int ni = 0; ni < 4; ni++) bfr[ni] = *(const short8*)(B1 + ni*1024);
      #pragma unroll
      for (int mi = 0; mi < 4; mi++)
        #pragma unroll
        for (int ni = 0; ni < 4; ni++)
          acc[mi][ni] = __builtin_amdgcn_mfma_f32_16x16x32_bf16(a[mi], bfr[ni], acc[mi][ni], 0, 0, 0);
    }
    __syncthreads();
  }

  const float* b2a = b2 + c*DM;
  const float* b2b = b2 + e1*DM;
  #pragma unroll
  for (int mi = 0; mi < 4; mi++){
    #pragma unroll
    for (int r = 0; r < 4; r++){
      int m = wr*64 + mi*16 + quad*4 + r;
      int i = m0 + m;
      if (i < n_c){
        int tk = rowtok[m];
        float* orow = out + (size_t)tk*DM + n0 + wc*64;
        #pragma unroll
        for (int ni = 0; ni < 4; ni++){
          int nl = ni*16 + col;
          int gn = n0 + wc*64 + nl;
          orow[nl] = 0.25f * (acc[mi][ni][r] + b2a[gn] + b2b[gn]);
        }
      }
    }
  }
}

extern "C" void kernel_launch(void* const* d_in, const int* in_sizes, int n_in,
                              void* d_out, int out_size, void* d_ws, size_t ws_size,
                              hipStream_t stream){
  const float* x   = (const float*)d_in[0];
  const int*   tok = (const int*)d_in[1];
  const float* W1  = (const float*)d_in[2];
  const float* b1  = (const float*)d_in[3];
  const float* W2  = (const float*)d_in[4];
  const float* b2  = (const float*)d_in[5];

  float* out        = (float*)d_out;                       // (B,T,D) f32
  float* ids_out    = out + (size_t)NTOK*DM;               // (B,T,2) as f32
  float* counts_out = ids_out + (size_t)NTOK*2;            // (E,)    as f32

  char* ws = (char*)d_ws;
  int* cnt  = (int*)ws;                                    // 8
  int* off  = cnt + 16;                                    // 9 (incl. total)
  int* list = (int*)(ws + 4096);                           // 8*CAP ints (192 KB)
  ushort_t* w1t = (ushort_t*)(ws + (1 << 20));             // [E][DF][DM] bf16 (16 MB)
  ushort_t* w2t = w1t + (size_t)NUM_E*DF*DM;               // [E][DM][DF] bf16 (16 MB)
  ushort_t* xb  = w2t + (size_t)NUM_E*DM*DF;               // [NTOK][DM]  bf16 (32 MB)
  ushort_t* H   = (ushort_t*)(ws + (65ull << 20));         // phase H (bf16)

  // choose phase width nb so the H region fits in ws
  size_t fixed_b = 65ull << 20;
  size_t avail = (ws_size > fixed_b) ? (ws_size - fixed_b) : 0;
  int nb = 0;
  for (int cand = 8; cand >= 1; cand >>= 1){
    size_t need = ((size_t)cand * 4096 + 1024) * (size_t)(2*DF) * 2;
    if (need <= avail){ nb = cand; break; }
  }
  if (nb == 0) nb = 1;   // last resort

  k_init<<<1, 64, 0, stream>>>(cnt);
  k_route<<<NTOK/256, 256, 0, stream>>>(tok, ids_out, cnt, list);
  k_finalize<<<1, 64, 0, stream>>>(cnt, off, counts_out);
  k_convert_x<<<(NTOK*DM/4)/256, 256, 0, stream>>>(x, xb);
  k_transpose_cvt<<<dim3(DF/64, DM/64, NUM_E), 256, 0, stream>>>(W1, w1t, DM, DF);
  k_transpose_cvt<<<dim3(DM/64, DF/64, NUM_E), 256, 0, stream>>>(W2, w2t, DF, DM);

  for (int c0 = 0; c0 < NUM_E; c0 += nb){
    k_gemm1<<<dim3(CAP/128, DF/128, 2*nb), 256, 0, stream>>>(
        xb, w1t, b1, cnt, off, list, H, c0);
    k_gemm2<<<dim3(CAP/128, DM/128, nb), 256, 0, stream>>>(
        H, w2t, b2, cnt, off, list, out, c0, nb);
  }
}

// Round 5
// 576.710 us; speedup vs baseline: 1.8731x; 1.2102x over previous
//
#include <hip/hip_runtime.h>
#include <math.h>

#define NUM_E 8
#define NTOK  32768      // B*T = 8*4096
#define TSEQ  4096
#define DM    512
#define DF    2048
#define CAP   6144       // per-bucket capacity (avg 4096, binomial sigma ~60)

typedef unsigned short ushort_t;
typedef __attribute__((ext_vector_type(8))) short short8;
typedef __attribute__((ext_vector_type(4))) float floatx4;

__device__ __forceinline__ unsigned short f2bf(float f){
  union { float f; unsigned int u; } v; v.f = f;
  unsigned int u = v.u;
  unsigned int r = (u + 0x7FFFu + ((u >> 16) & 1u)) >> 16;  // RNE
  return (unsigned short)r;
}

// tanh-approx gelu, reduced: 0.5h(1+tanh(0.79788456(h+0.044715h^3)))
//                          = h * sigmoid(1.5957691h + 0.0713548163h^3)
__device__ __forceinline__ float gelu_fast(float h){
  float z = h * (1.5957691216057308f + 0.0713548162726009f * h * h);
  float e = __expf(-z);
  return h * __builtin_amdgcn_rcpf(1.0f + e);
}

__device__ __forceinline__ void gld_lds16(const void* g, void* l){
  __builtin_amdgcn_global_load_lds(
      (const __attribute__((address_space(1))) unsigned int*)g,
      (__attribute__((address_space(3))) unsigned int*)l, 16, 0, 0);
}

__global__ void k_init(int* cnt){
  if (threadIdx.x < NUM_E) cnt[threadIdx.x] = 0;
}

// hierarchical routing: LDS per-block counts -> 8 global atomics per block.
// (previous flat version: 32768 device atomics on one cache line = 125us stall)
__global__ __launch_bounds__(1024) void k_route(
    const int* __restrict__ tok, float* __restrict__ ids_out,
    int* __restrict__ cnt, int* __restrict__ list){
  __shared__ int lcnt[NUM_E];
  __shared__ int lbase[NUM_E];
  int tid = threadIdx.x;
  if (tid < NUM_E) lcnt[tid] = 0;
  __syncthreads();
  int flat = blockIdx.x * 1024 + tid;                  // 0..NTOK-1
  int b = flat >> 12;                                  // T = 4096
  int t = tok[flat];
  int base = b * TSEQ + t;                             // b*T + token
  int e0 = base & 7;
  int e1 = (base + 1) & 7;
  ids_out[2*flat]   = (float)e0;
  ids_out[2*flat+1] = (float)e1;
  int lpos = atomicAdd(&lcnt[e0], 1);                  // LDS atomic: cheap
  __syncthreads();
  if (tid < NUM_E) lbase[tid] = atomicAdd(&cnt[tid], lcnt[tid]);
  __syncthreads();
  int pos = lbase[e0] + lpos;
  if (pos < CAP) list[e0*CAP + pos] = flat;
}

__global__ void k_finalize(const int* __restrict__ cnt, int* __restrict__ off,
                           float* __restrict__ counts_out){
  int tid = threadIdx.x;
  if (tid == 0){
    int s = 0;
    for (int c = 0; c < NUM_E; c++){ off[c] = s; s += cnt[c]; }
    off[NUM_E] = s;                                    // total sentinel
  }
  if (tid < NUM_E)
    counts_out[tid] = (float)(cnt[tid] + cnt[(tid + 7) & 7]); // slot0(bucket e) + slot1(bucket e-1)
}

__global__ void k_convert_x(const float* __restrict__ x, ushort_t* __restrict__ xb){
  int i = blockIdx.x * blockDim.x + threadIdx.x;       // one float4 per thread
  float4 v = ((const float4*)x)[i];
  ushort4 o;
  o.x = f2bf(v.x); o.y = f2bf(v.y); o.z = f2bf(v.z); o.w = f2bf(v.w);
  ((ushort4*)xb)[i] = o;
}

// in: [E][R][C] fp32  ->  out: [E][C][R] bf16
__global__ void k_transpose_cvt(const float* __restrict__ in, ushort_t* __restrict__ out,
                                int R, int C){
  __shared__ ushort_t s[64][65];
  int e = blockIdx.z;
  int c0 = blockIdx.x * 64, r0 = blockIdx.y * 64;
  const float* ine = in + (size_t)e * R * C;
  ushort_t* oute = out + (size_t)e * R * C;
  int tx = threadIdx.x & 63, ty = threadIdx.x >> 6;
  for (int rr = ty; rr < 64; rr += 4)
    s[rr][tx] = f2bf(ine[(size_t)(r0+rr)*C + c0 + tx]);
  __syncthreads();
  for (int cc = ty; cc < 64; cc += 4)
    oute[(size_t)(c0+cc)*R + r0 + tx] = s[tx][cc];
}

// LDS tile layout (both GEMMs): 128 rows x 64 ushort, row-major; within each
// row the eight 16B chunks are XOR-swizzled: chunk c of row r sits at slot c^(r&7).
// Staging lane L fetches global chunk (L&7)^(L>>3); fragment reads use
// ((quad+4*ks)^(col&7)) — spreads 64 lanes 8-per-bank-group (conflict-free).

// GEMM1: for bucket c (phase-relative), slot s (expert e=(c+s)%8):
//   H[(off[c]-off[c0])+i][s*DF + n] = gelu( x[list[c][i]] @ W1[e] + b1[e] )   (bf16)
__global__ __launch_bounds__(256, 4) void k_gemm1(
    const ushort_t* __restrict__ xb, const ushort_t* __restrict__ w1t,
    const float* __restrict__ b1,
    const int* __restrict__ cnt, const int* __restrict__ off,
    const int* __restrict__ list, ushort_t* __restrict__ H, int c0)
{
  int c = c0 + (blockIdx.z >> 1), slot = blockIdx.z & 1;
  int e = (c + slot) & 7;
  int n_c = cnt[c];
  int m0 = blockIdx.x * 128;
  if (m0 >= n_c) return;
  int n0 = blockIdx.y * 128;

  __shared__ alignas(16) ushort_t As[128*64];
  __shared__ alignas(16) ushort_t Bs[128*64];
  __shared__ unsigned int rowoff[128];

  int tid = threadIdx.x;
  int lane = tid & 63, w = tid >> 6;

  if (tid < 128){
    int i = m0 + tid;
    int tk = list[c*CAP + ((i < n_c) ? i : 0)];
    rowoff[tid] = (unsigned int)tk * (DM*2);
  }
  __syncthreads();

  int rl = lane >> 3;                 // row within 8-row staging block
  int cc = (lane & 7) ^ rl;           // swizzled source chunk
  unsigned int aoff[4], boff[4];
  const char* w1te = (const char*)w1t + (size_t)e * ((size_t)DF*DM*2);
  #pragma unroll
  for (int j = 0; j < 4; j++){
    int r = j*32 + w*8 + rl;
    aoff[j] = rowoff[r] + (unsigned int)cc*16u;
    boff[j] = (unsigned int)(n0 + r) * (DM*2) + (unsigned int)cc*16u;
  }

  floatx4 acc[4][4];
  #pragma unroll
  for (int a = 0; a < 4; a++)
    #pragma unroll
    for (int q = 0; q < 4; q++) acc[a][q] = floatx4{0.f,0.f,0.f,0.f};

  int wr = w >> 1, wc = w & 1;
  int col = lane & 15, quad = lane >> 4;
  int xa = col & 7;
  const ushort_t* A0 = As + (wr*64 + col)*64 + (quad ^ xa)*8;        // ks=0
  const ushort_t* A1 = As + (wr*64 + col)*64 + ((quad + 4) ^ xa)*8;  // ks=1
  const ushort_t* B0 = Bs + (wc*64 + col)*64 + (quad ^ xa)*8;
  const ushort_t* B1 = Bs + (wc*64 + col)*64 + ((quad + 4) ^ xa)*8;
  char* AsW = (char*)As + w*1024;
  char* BsW = (char*)Bs + w*1024;

  for (int k0 = 0; k0 < DM; k0 += 64){
    #pragma unroll
    for (int j = 0; j < 4; j++){
      gld_lds16((const char*)xb + aoff[j] + k0*2, AsW + j*4096);
      gld_lds16(w1te + boff[j] + k0*2, BsW + j*4096);
    }
    __syncthreads();
    {
      short8 a[4], bfr[4];
      #pragma unroll
      for (int mi = 0; mi < 4; mi++) a[mi] = *(const short8*)(A0 + mi*1024);
      #pragma unroll
      for (int ni = 0; ni < 4; ni++) bfr[ni] = *(const short8*)(B0 + ni*1024);
      #pragma unroll
      for (int mi = 0; mi < 4; mi++)
        #pragma unroll
        for (int ni = 0; ni < 4; ni++)
          acc[mi][ni] = __builtin_amdgcn_mfma_f32_16x16x32_bf16(a[mi], bfr[ni], acc[mi][ni], 0, 0, 0);
      #pragma unroll
      for (int mi = 0; mi < 4; mi++) a[mi] = *(const short8*)(A1 + mi*1024);
      #pragma unroll
      for (int ni = 0; ni < 4; ni++) bfr[ni] = *(const short8*)(B1 + ni*1024);
      #pragma unroll
      for (int mi = 0; mi < 4; mi++)
        #pragma unroll
        for (int ni = 0; ni < 4; ni++)
          acc[mi][ni] = __builtin_amdgcn_mfma_f32_16x16x32_bf16(a[mi], bfr[ni], acc[mi][ni], 0, 0, 0);
    }
    __syncthreads();
  }

  int hbase = off[c] - off[c0];
  const float* b1e = b1 + e*DF;
  #pragma unroll
  for (int mi = 0; mi < 4; mi++){
    #pragma unroll
    for (int r = 0; r < 4; r++){
      int m = wr*64 + mi*16 + quad*4 + r;
      int i = m0 + m;
      if (i < n_c){
        size_t hrow = (size_t)(hbase + i)*(2*DF) + (size_t)slot*DF + n0 + wc*64;
        #pragma unroll
        for (int ni = 0; ni < 4; ni++){
          int nl = ni*16 + col;
          float v = acc[mi][ni][r] + b1e[n0 + wc*64 + nl];
          H[hrow + nl] = f2bf(gelu_fast(v));
        }
      }
    }
  }
}

// GEMM2: for bucket c (experts c, c+1):
//   out[list[c][i]][n] = 0.25*( H[(off[c]-off[c0])+i][0:4096] @ [W2[c];W2[c+1]] + b2[c] + b2[c+1] )
__global__ __launch_bounds__(256, 4) void k_gemm2(
    const ushort_t* __restrict__ H, const ushort_t* __restrict__ w2t,
    const float* __restrict__ b2,
    const int* __restrict__ cnt, const int* __restrict__ off,
    const int* __restrict__ list, float* __restrict__ out, int c0, int nb)
{
  int c = c0 + blockIdx.z;
  int e1 = (c + 1) & 7;
  int n_c = cnt[c];
  int m0 = blockIdx.x * 128;
  if (m0 >= n_c) return;
  int n0 = blockIdx.y * 128;

  __shared__ alignas(16) ushort_t As[128*64];
  __shared__ alignas(16) ushort_t Bs[128*64];
  __shared__ int rowtok[128];

  int tid = threadIdx.x;
  int lane = tid & 63, w = tid >> 6;
  int rowbase = off[c] - off[c0];
  int phaseTok = off[c0 + nb] - off[c0];

  if (tid < 128){
    int i = m0 + tid;
    rowtok[tid] = list[c*CAP + ((i < n_c) ? i : 0)];
  }

  int rl = lane >> 3;
  int cc = (lane & 7) ^ rl;
  unsigned int aoff[4], boff[4];
  #pragma unroll
  for (int j = 0; j < 4; j++){
    int r = j*32 + w*8 + rl;
    int rg = rowbase + m0 + r;
    if (rg > phaseTok - 1) rg = phaseTok - 1;           // stay inside phase H
    aoff[j] = (unsigned int)rg * (2*DF*2) + (unsigned int)cc*16u;
    boff[j] = (unsigned int)(n0 + r) * (DF*2) + (unsigned int)cc*16u;
  }
  const char* bb0 = (const char*)w2t + (size_t)c  * ((size_t)DM*DF*2);
  const char* bb1 = (const char*)w2t + (size_t)e1 * ((size_t)DM*DF*2);

  floatx4 acc[4][4];
  #pragma unroll
  for (int a = 0; a < 4; a++)
    #pragma unroll
    for (int q = 0; q < 4; q++) acc[a][q] = floatx4{0.f,0.f,0.f,0.f};

  int wr = w >> 1, wc = w & 1;
  int col = lane & 15, quad = lane >> 4;
  int xa = col & 7;
  const ushort_t* A0 = As + (wr*64 + col)*64 + (quad ^ xa)*8;
  const ushort_t* A1 = As + (wr*64 + col)*64 + ((quad + 4) ^ xa)*8;
  const ushort_t* B0 = Bs + (wc*64 + col)*64 + (quad ^ xa)*8;
  const ushort_t* B1 = Bs + (wc*64 + col)*64 + ((quad + 4) ^ xa)*8;
  char* AsW = (char*)As + w*1024;
  char* BsW = (char*)Bs + w*1024;

  for (int k0 = 0; k0 < 2*DF; k0 += 64){
    const char* bb = (k0 < DF) ? (bb0 + k0*2) : (bb1 + (k0 - DF)*2);
    #pragma unroll
    for (int j = 0; j < 4; j++){
      gld_lds16((const char*)H + aoff[j] + k0*2, AsW + j*4096);
      gld_lds16(bb + boff[j], BsW + j*4096);
    }
    __syncthreads();
    {
      short8 a[4], bfr[4];
      #pragma unroll
      for (int mi = 0; mi < 4; mi++) a[mi] = *(const short8*)(A0 + mi*1024);
      #pragma unroll
      for (int ni = 0; ni < 4; ni++) bfr[ni] = *(const short8*)(B0 + ni*1024);
      #pragma unroll
      for (int mi = 0; mi < 4; mi++)
        #pragma unroll
        for (int ni = 0; ni < 4; ni++)
          acc[mi][ni] = __builtin_amdgcn_mfma_f32_16x16x32_bf16(a[mi], bfr[ni], acc[mi][ni], 0, 0, 0);
      #pragma unroll
      for (int mi = 0; mi < 4; mi++) a[mi] = *(const short8*)(A1 + mi*1024);
      #pragma unroll
      for (int ni = 0; ni < 4; ni++) bfr[ni] = *(const short8*)(B1 + ni*1024);
      #pragma unroll
      for (int mi = 0; mi < 4; mi++)
        #pragma unroll
        for (int ni = 0; ni < 4; ni++)
          acc[mi][ni] = __builtin_amdgcn_mfma_f32_16x16x32_bf16(a[mi], bfr[ni], acc[mi][ni], 0, 0, 0);
    }
    __syncthreads();
  }

  const float* b2a = b2 + c*DM;
  const float* b2b = b2 + e1*DM;
  #pragma unroll
  for (int mi = 0; mi < 4; mi++){
    #pragma unroll
    for (int r = 0; r < 4; r++){
      int m = wr*64 + mi*16 + quad*4 + r;
      int i = m0 + m;
      if (i < n_c){
        int tk = rowtok[m];
        float* orow = out + (size_t)tk*DM + n0 + wc*64;
        #pragma unroll
        for (int ni = 0; ni < 4; ni++){
          int nl = ni*16 + col;
          int gn = n0 + wc*64 + nl;
          orow[nl] = 0.25f * (acc[mi][ni][r] + b2a[gn] + b2b[gn]);
        }
      }
    }
  }
}

extern "C" void kernel_launch(void* const* d_in, const int* in_sizes, int n_in,
                              void* d_out, int out_size, void* d_ws, size_t ws_size,
                              hipStream_t stream){
  const float* x   = (const float*)d_in[0];
  const int*   tok = (const int*)d_in[1];
  const float* W1  = (const float*)d_in[2];
  const float* b1  = (const float*)d_in[3];
  const float* W2  = (const float*)d_in[4];
  const float* b2  = (const float*)d_in[5];

  float* out        = (float*)d_out;                       // (B,T,D) f32
  float* ids_out    = out + (size_t)NTOK*DM;               // (B,T,2) as f32
  float* counts_out = ids_out + (size_t)NTOK*2;            // (E,)    as f32

  char* ws = (char*)d_ws;
  int* cnt  = (int*)ws;                                    // 8
  int* off  = cnt + 16;                                    // 9 (incl. total)
  int* list = (int*)(ws + 4096);                           // 8*CAP ints (192 KB)
  ushort_t* w1t = (ushort_t*)(ws + (1 << 20));             // [E][DF][DM] bf16 (16 MB)
  ushort_t* w2t = w1t + (size_t)NUM_E*DF*DM;               // [E][DM][DF] bf16 (16 MB)
  ushort_t* xb  = w2t + (size_t)NUM_E*DM*DF;               // [NTOK][DM]  bf16 (32 MB)
  ushort_t* H   = (ushort_t*)(ws + (65ull << 20));         // phase H (bf16)

  // choose phase width nb so the H region fits in ws
  size_t fixed_b = 65ull << 20;
  size_t avail = (ws_size > fixed_b) ? (ws_size - fixed_b) : 0;
  int nb = 0;
  for (int cand = 8; cand >= 1; cand >>= 1){
    size_t need = ((size_t)cand * 4096 + 1024) * (size_t)(2*DF) * 2;
    if (need <= avail){ nb = cand; break; }
  }
  if (nb == 0) nb = 1;   // last resort

  k_init<<<1, 64, 0, stream>>>(cnt);
  k_route<<<NTOK/1024, 1024, 0, stream>>>(tok, ids_out, cnt, list);
  k_finalize<<<1, 64, 0, stream>>>(cnt, off, counts_out);
  k_convert_x<<<(NTOK*DM/4)/256, 256, 0, stream>>>(x, xb);
  k_transpose_cvt<<<dim3(DF/64, DM/64, NUM_E), 256, 0, stream>>>(W1, w1t, DM, DF);
  k_transpose_cvt<<<dim3(DM/64, DF/64, NUM_E), 256, 0, stream>>>(W2, w2t, DF, DM);

  for (int c0 = 0; c0 < NUM_E; c0 += nb){
    k_gemm1<<<dim3(CAP/128, DF/128, 2*nb), 256, 0, stream>>>(
        xb, w1t, b1, cnt, off, list, H, c0);
    k_gemm2<<<dim3(CAP/128, DM/128, nb), 256, 0, stream>>>(
        H, w2t, b2, cnt, off, list, out, c0, nb);
  }
}